// Round 10
// baseline (157.335 us; speedup 1.0000x reference)
//
#include <hip/hip_runtime.h>
#include <hip/hip_bf16.h>
#include <math.h>

typedef unsigned short u16;
typedef unsigned int u32;
typedef __bf16 bf16x8 __attribute__((ext_vector_type(8)));
typedef float f32x4 __attribute__((ext_vector_type(4)));

// B=8, T=128, S=512, E=D=512, fp32 in/out. d_out: h_tilde | wc | attn (fp32).
#define OUT_WC   524288LL
#define OUT_ATTN 1048576LL
#define C2 2.8853900817779268f   // 2*log2(e)
#define LOG2E 1.4426950408889634f
#define LAS 40                   // hout LDS stride (u16)
#define PLAS 36                  // proj LDS stride: 72B rows -> 18*r mod 32 hits all 16 banks

__device__ inline u16 f2b(float f) {
    return (u16)((__float_as_uint(f) + 0x8000u) >> 16);
}
__device__ inline float b2f(u16 v) { return __uint_as_float(((u32)v) << 16); }
__device__ inline u32 pkcvt(float x, float y) {
    __hip_bfloat162 h = __float22bfloat162_rn(make_float2(x, y));
    return *(u32*)&h;
}
__device__ inline float tanh_fast(float x) {
    return 1.f - 2.f * __builtin_amdgcn_rcpf(__builtin_amdgcn_exp2f(C2 * x) + 1.f);
}

// =============== tobf: fp32 -> bf16 pre-convert (enc|hidden|Wattn|Wout) ======
__global__ __launch_bounds__(256) void tobf(
    const float* __restrict__ enc, const float* __restrict__ hidden,
    const float* __restrict__ Wattn, const float* __restrict__ Wout,
    u16* __restrict__ dst)
{
    long long i = ((long long)blockIdx.x * 256 + threadIdx.x) * 8;
    const float* src; long long off;
    if (i < 2097152)      { src = enc;    off = i; }
    else if (i < 2621440) { src = hidden; off = i - 2097152; }
    else if (i < 3145728) { src = Wattn;  off = i - 2621440; }
    else                  { src = Wout;   off = i - 3145728; }
    float4 v0 = *(const float4*)(src + off);
    float4 v1 = *(const float4*)(src + off + 4);
    *(uint4*)(dst + i) = make_uint4(pkcvt(v0.x, v0.y), pkcvt(v0.z, v0.w),
                                    pkcvt(v1.x, v1.y), pkcvt(v1.z, v1.w));
}

// =============== proj: 128x128-tile NT GEMM, 192 blocks ======================
// blocks 0..127:   ept[b][k][s] = exp2(C2 * We@enc^T)  (bf16 out)  [4x4 per b]
// blocks 128..159: hp = C2*(hidden@Wh^T + battn)       (f32)       [8x4]
// blocks 160..191: hh = hidden@Wout[:,512:]^T -> d_out (f32)       [8x4]
// 4 waves in 2x2; wave computes 64x64 (4x4 MFMA 16x16x32). VGPR double-buffer.
__global__ __launch_bounds__(256) void proj(
    const u16* __restrict__ hidden_bf, const u16* __restrict__ enc_bf,
    const u16* __restrict__ Wattn_bf, const float* __restrict__ battn,
    const u16* __restrict__ Wout_bf,
    float* __restrict__ hp, u16* __restrict__ ept, float* __restrict__ hh)
{
    __shared__ u16 lA[128 * PLAS];
    __shared__ u16 lB[128 * PLAS];
    const int tid = threadIdx.x;
    const int wvi = tid >> 6, ln = tid & 63;
    const int wm = wvi >> 1, wn = wvi & 1;
    const int l16 = ln & 15, quad = ln >> 4;
    const int blk = blockIdx.x;
    int mode, bx, by, zz = 0, lda, ldb;
    const u16 *A, *B;
    if (blk < 128) {
        mode = 0;
        zz = blk >> 4; by = (blk >> 2) & 3; bx = blk & 3;
        A = Wattn_bf + 512; lda = 1024;
        B = enc_bf + (long long)zz * 262144; ldb = 512;
    } else if (blk < 160) {
        mode = 1;
        int i = blk - 128; by = i >> 2; bx = i & 3;
        A = hidden_bf; lda = 512;
        B = Wattn_bf; ldb = 1024;
    } else {
        mode = 2;
        int i = blk - 160; by = i >> 2; bx = i & 3;
        A = hidden_bf; lda = 512;
        B = Wout_bf + 512; ldb = 1024;
    }
    const int m0 = by * 128, n0 = bx * 128;
    // staging: thread t -> rows sr, sr+64; k-chunk sc (8 elems)
    const int sr = tid >> 2, sc = (tid & 3) * 8;
    const u16* Ap0 = A + (long long)(m0 + sr) * lda + sc;
    const u16* Ap1 = A + (long long)(m0 + sr + 64) * lda + sc;
    const u16* Bp0 = B + (long long)(n0 + sr) * ldb + sc;
    const u16* Bp1 = B + (long long)(n0 + sr + 64) * ldb + sc;

    f32x4 acc[4][4] = {};
    uint4 ra0 = *(const uint4*)(Ap0);
    uint4 ra1 = *(const uint4*)(Ap1);
    uint4 rb0 = *(const uint4*)(Bp0);
    uint4 rb1 = *(const uint4*)(Bp1);

    for (int k0 = 0; k0 < 512; k0 += 32) {
        __syncthreads();
        *(uint4*)&lA[sr * PLAS + sc]        = ra0;
        *(uint4*)&lA[(sr + 64) * PLAS + sc] = ra1;
        *(uint4*)&lB[sr * PLAS + sc]        = rb0;
        *(uint4*)&lB[(sr + 64) * PLAS + sc] = rb1;
        __syncthreads();
        if (k0 + 32 < 512) {           // prefetch next k-tile during MFMA burst
            ra0 = *(const uint4*)(Ap0 + k0 + 32);
            ra1 = *(const uint4*)(Ap1 + k0 + 32);
            rb0 = *(const uint4*)(Bp0 + k0 + 32);
            rb1 = *(const uint4*)(Bp1 + k0 + 32);
        }
        bf16x8 af[4], bfr[4];
        #pragma unroll
        for (int i = 0; i < 4; ++i) {
            af[i]  = *(const bf16x8*)&lA[(wm * 64 + i * 16 + l16) * PLAS + quad * 8];
            bfr[i] = *(const bf16x8*)&lB[(wn * 64 + i * 16 + l16) * PLAS + quad * 8];
        }
        #pragma unroll
        for (int i = 0; i < 4; ++i)
            #pragma unroll
            for (int j = 0; j < 4; ++j)
                acc[i][j] = __builtin_amdgcn_mfma_f32_16x16x32_bf16(af[i], bfr[j], acc[i][j], 0, 0, 0);
    }

    #pragma unroll
    for (int i = 0; i < 4; ++i) {
        #pragma unroll
        for (int j = 0; j < 4; ++j) {
            #pragma unroll
            for (int r = 0; r < 4; ++r) {
                int m = m0 + wm * 64 + i * 16 + quad * 4 + r;
                int n = n0 + wn * 64 + j * 16 + l16;
                float v = acc[i][j][r];
                if (mode == 0)
                    ept[(long long)zz * 262144 + (long long)m * 512 + n] =
                        f2b(__builtin_amdgcn_exp2f(C2 * v));
                else if (mode == 1)
                    hp[(long long)m * 512 + n] = C2 * (v + battn[n]);
                else
                    hh[(long long)m * 512 + n] = v;
            }
        }
    }
}

// =============== block reductions (8-wave, 512 threads) ======================
__device__ inline float wred_sum(float v) {
    #pragma unroll
    for (int i = 32; i > 0; i >>= 1) v += __shfl_xor(v, i);
    return v;
}
__device__ inline float bred_sum8(float v, float* red, int tid) {
    v = wred_sum(v);
    __syncthreads();
    if ((tid & 63) == 0) red[tid >> 6] = v;
    __syncthreads();
    float s = 0.f;
    #pragma unroll
    for (int i = 0; i < 8; ++i) s += red[i];
    return s;
}
__device__ inline void bred2_max(float v0, float v1, float* red, int tid,
                                 float* o0, float* o1) {
    #pragma unroll
    for (int i = 32; i > 0; i >>= 1) {
        v0 = fmaxf(v0, __shfl_xor(v0, i));
        v1 = fmaxf(v1, __shfl_xor(v1, i));
    }
    __syncthreads();
    if ((tid & 63) == 0) { red[tid >> 6] = v0; red[8 + (tid >> 6)] = v1; }
    __syncthreads();
    float a0 = red[0], a1 = red[8];
    #pragma unroll
    for (int i = 1; i < 8; ++i) { a0 = fmaxf(a0, red[i]); a1 = fmaxf(a1, red[8 + i]); }
    *o0 = a0; *o1 = a1;
}
__device__ inline void bred2_sum(float v0, float v1, float* red, int tid,
                                 float* o0, float* o1) {
    #pragma unroll
    for (int i = 32; i > 0; i >>= 1) { v0 += __shfl_xor(v0, i); v1 += __shfl_xor(v1, i); }
    __syncthreads();
    if ((tid & 63) == 0) { red[tid >> 6] = v0; red[8 + (tid >> 6)] = v1; }
    __syncthreads();
    float a0 = 0.f, a1 = 0.f;
    #pragma unroll
    for (int i = 0; i < 8; ++i) { a0 += red[i]; a1 += red[8 + i]; }
    *o0 = a0; *o1 = a1;
}

// =============== energies + masked softmax + wc (fused, unchanged R9) ========
__device__ inline void proc8(uint4 c, float4 hw, float* a0, float* a1) {
    u32 cc[4] = {c.x, c.y, c.z, c.w};
    #pragma unroll
    for (int i = 0; i < 4; ++i) {
        float xl = __uint_as_float(cc[i] << 16);
        float xh = __uint_as_float(cc[i] & 0xFFFF0000u);
        float rl0 = __builtin_amdgcn_rcpf(fmaf(hw.x, xl, 1.f));
        float rh0 = __builtin_amdgcn_rcpf(fmaf(hw.x, xh, 1.f));
        float rl1 = __builtin_amdgcn_rcpf(fmaf(hw.y, xl, 1.f));
        float rh1 = __builtin_amdgcn_rcpf(fmaf(hw.y, xh, 1.f));
        a0[2*i]   = fmaf(hw.z, rl0, a0[2*i]);
        a0[2*i+1] = fmaf(hw.z, rh0, a0[2*i+1]);
        a1[2*i]   = fmaf(hw.z, rl1, a1[2*i]);
        a1[2*i+1] = fmaf(hw.z, rh1, a1[2*i+1]);
    }
}

__global__ __launch_bounds__(512) void energies(
    const float* __restrict__ maskp, const float* __restrict__ hp,
    const u16* __restrict__ ept, const float* __restrict__ Wv,
    const float* __restrict__ bvp, const u16* __restrict__ enc_bf,
    float* __restrict__ attn, float* __restrict__ wc)
{
    __shared__ __align__(16) float4 hpw[512];
    __shared__ float pa[2][8][512];
    __shared__ __align__(16) float2 aL[512];
    __shared__ float red[16];
    const int tid = threadIdx.x;
    const int b = blockIdx.x >> 6;
    const int t0 = (blockIdx.x & 63) * 2;

    float w = Wv[tid];
    float h0 = hp[(long long)(b * 128 + t0) * 512 + tid];
    float h1 = hp[(long long)(b * 128 + t0 + 1) * 512 + tid];
    hpw[tid] = make_float4(__builtin_amdgcn_exp2f(h0), __builtin_amdgcn_exp2f(h1), w, 0.f);
    float sumWv = bred_sum8(w, red, tid);

    const int kg = tid >> 6, sl = tid & 63;
    const int s0 = sl * 8;
    const u16* eb = ept + (long long)b * 262144 + (kg * 64) * 512 + s0;
    const float4* hq = &hpw[kg * 64];

    float a0[8] = {0,0,0,0,0,0,0,0}, a1[8] = {0,0,0,0,0,0,0,0};
    uint4 c0 = *(const uint4*)(eb);
    uint4 c1 = *(const uint4*)(eb + 512);
    uint4 c2 = *(const uint4*)(eb + 1024);
    uint4 c3 = *(const uint4*)(eb + 1536);
    for (int kk = 0; kk < 60; kk += 4) {
        const u16* nb = eb + (kk + 4) * 512;
        uint4 n0 = *(const uint4*)(nb);
        uint4 n1 = *(const uint4*)(nb + 512);
        uint4 n2 = *(const uint4*)(nb + 1024);
        uint4 n3 = *(const uint4*)(nb + 1536);
        proc8(c0, hq[kk],     a0, a1);
        proc8(c1, hq[kk + 1], a0, a1);
        proc8(c2, hq[kk + 2], a0, a1);
        proc8(c3, hq[kk + 3], a0, a1);
        c0 = n0; c1 = n1; c2 = n2; c3 = n3;
    }
    proc8(c0, hq[60], a0, a1);
    proc8(c1, hq[61], a0, a1);
    proc8(c2, hq[62], a0, a1);
    proc8(c3, hq[63], a0, a1);

    *(float4*)&pa[0][kg][s0]     = make_float4(a0[0], a0[1], a0[2], a0[3]);
    *(float4*)&pa[0][kg][s0 + 4] = make_float4(a0[4], a0[5], a0[6], a0[7]);
    *(float4*)&pa[1][kg][s0]     = make_float4(a1[0], a1[1], a1[2], a1[3]);
    *(float4*)&pa[1][kg][s0 + 4] = make_float4(a1[4], a1[5], a1[6], a1[7]);
    __syncthreads();

    const int s = tid;
    float A0 = 0.f, A1 = 0.f;
    #pragma unroll
    for (int g = 0; g < 8; ++g) { A0 += pa[0][g][s]; A1 += pa[1][g][s]; }
    float mv = maskp[(long long)b * 512 + s];
    float bv0 = bvp[0];
    float r0 = (bv0 + sumWv - 2.f * A0) * mv; r0 *= mv;
    float r1 = (bv0 + sumWv - 2.f * A1) * mv; r1 *= mv;

    float mx0, mx1;
    bred2_max(r0, r1, red, tid, &mx0, &mx1);
    float ex0 = __builtin_amdgcn_exp2f((r0 - mx0) * LOG2E) * mv;
    float ex1 = __builtin_amdgcn_exp2f((r1 - mx1) * LOG2E) * mv;
    float sm0, sm1;
    bred2_sum(ex0, ex1, red, tid, &sm0, &sm1);
    float at0 = ex0 * (1.f / (sm0 + 1e-6f));
    float at1 = ex1 * (1.f / (sm1 + 1e-6f));
    attn[(long long)(b * 128 + t0) * 512 + s]     = at0;
    attn[(long long)(b * 128 + t0 + 1) * 512 + s] = at1;
    aL[s] = make_float2(at0, at1);
    __syncthreads();

    const u16* encb = enc_bf + (long long)b * 262144 + tid;
    const float4* aL4 = (const float4*)aL;
    float acc0 = 0.f, acc1 = 0.f;
    for (int ss = 0; ss < 512; ss += 8) {
        float ev[8];
        #pragma unroll
        for (int i = 0; i < 8; ++i) ev[i] = b2f(encb[(ss + i) * 512]);
        #pragma unroll
        for (int i = 0; i < 4; ++i) {
            float4 ap = aL4[(ss >> 1) + i];
            acc0 = fmaf(ap.x, ev[2*i],   acc0);
            acc1 = fmaf(ap.y, ev[2*i],   acc1);
            acc0 = fmaf(ap.z, ev[2*i+1], acc0);
            acc1 = fmaf(ap.w, ev[2*i+1], acc1);
        }
    }
    wc[(long long)(b * 128 + t0) * 512 + tid]     = acc0;
    wc[(long long)(b * 128 + t0 + 1) * 512 + tid] = acc1;
}

// =============== hout: h_tilde = tanh(wc @ Wout[:,:512]^T + hh) ==============
__global__ __launch_bounds__(256) void hout_k(
    const float* __restrict__ wc, const u16* __restrict__ Wout_bf,
    float* __restrict__ out)
{
    __shared__ u16 lA[32 * LAS];
    __shared__ u16 lB[64 * LAS];
    const int tid = threadIdx.x;
    const int wvi = tid >> 6, ln = tid & 63;
    const int l16 = ln & 15, quad = ln >> 4;
    const int msub = wvi & 1, npair = wvi >> 1;
    const int m0 = blockIdx.y * 32, n0 = blockIdx.x * 64;
    const int rowA = tid >> 3, kofA = (tid & 7) * 4;
    const int rowB = tid >> 2, kofB = (tid & 3) * 8;
    f32x4 acc0 = {0,0,0,0}, acc1 = {0,0,0,0};

    for (int k0 = 0; k0 < 512; k0 += 32) {
        float4 av = *(const float4*)(wc + (long long)(m0 + rowA) * 512 + k0 + kofA);
        uint4 bv = *(const uint4*)(Wout_bf + (long long)(n0 + rowB) * 1024 + k0 + kofB);
        __syncthreads();
        *(uint2*)&lA[rowA * LAS + kofA] = make_uint2(pkcvt(av.x, av.y), pkcvt(av.z, av.w));
        int kk = kofB ^ (((rowB >> 3) & 3) << 3);
        *(uint4*)&lB[rowB * LAS + kk] = bv;
        __syncthreads();
        bf16x8 a = *(const bf16x8*)&lA[(msub * 16 + l16) * LAS + quad * 8];
        int nr0 = npair * 32 + l16, nr1 = nr0 + 16;
        bf16x8 b0 = *(const bf16x8*)&lB[nr0 * LAS + (quad * 8 ^ (((nr0 >> 3) & 3) << 3))];
        bf16x8 b1 = *(const bf16x8*)&lB[nr1 * LAS + (quad * 8 ^ (((nr1 >> 3) & 3) << 3))];
        acc0 = __builtin_amdgcn_mfma_f32_16x16x32_bf16(a, b0, acc0, 0, 0, 0);
        acc1 = __builtin_amdgcn_mfma_f32_16x16x32_bf16(a, b1, acc1, 0, 0, 0);
    }
    #pragma unroll
    for (int j = 0; j < 2; ++j) {
        const f32x4& a = j ? acc1 : acc0;
        #pragma unroll
        for (int r = 0; r < 4; ++r) {
            int m = m0 + msub * 16 + quad * 4 + r;
            int n = n0 + npair * 32 + j * 16 + l16;
            long long idx = (long long)m * 512 + n;
            out[idx] = tanh_fast(a[r] + out[idx]);   // out holds hh
        }
    }
}

extern "C" void kernel_launch(void* const* d_in, const int* in_sizes, int n_in,
                              void* d_out, int out_size, void* d_ws, size_t ws_size,
                              hipStream_t stream)
{
    const float* hidden = (const float*)d_in[0];
    const float* enc    = (const float*)d_in[1];
    const float* mask   = (const float*)d_in[2];
    const float* Wattn  = (const float*)d_in[3];
    const float* battn  = (const float*)d_in[4];
    const float* Wv     = (const float*)d_in[5];
    const float* bvp    = (const float*)d_in[6];
    const float* Wout   = (const float*)d_in[7];
    float* out = (float*)d_out;

    float* hp  = (float*)d_ws;                      // @0   2MB fp32
    u16*   ept = (u16*)((char*)d_ws + (2 << 20));   // @2M  4MB bf16 (exp2 domain)
    u16*   bfp = (u16*)((char*)d_ws + (6 << 20));   // @6M  7MB bf16 pool
    u16* enc_bf    = bfp;
    u16* hidden_bf = bfp + 2097152;
    u16* Wattn_bf  = bfp + 2621440;
    u16* Wout_bf   = bfp + 3145728;

    tobf<<<1792, 256, 0, stream>>>(enc, hidden, Wattn, Wout, bfp);
    proj<<<192, 256, 0, stream>>>(hidden_bf, enc_bf, Wattn_bf, battn, Wout_bf,
                                  hp, ept, out /* hh in-place */);
    energies<<<512, 512, 0, stream>>>(mask, hp, ept, Wv, bvp, enc_bf,
                                      out + OUT_ATTN, out + OUT_WC);
    hout_k<<<dim3(8, 32, 1), 256, 0, stream>>>(out + OUT_WC, Wout_bf, out);
}

// Round 11
// 153.452 us; speedup vs baseline: 1.0253x; 1.0253x over previous
//
#include <hip/hip_runtime.h>
#include <hip/hip_bf16.h>
#include <math.h>

typedef unsigned short u16;
typedef unsigned int u32;
typedef __bf16 bf16x8 __attribute__((ext_vector_type(8)));
typedef float f32x4 __attribute__((ext_vector_type(4)));

// B=8, T=128, S=512, E=D=512, fp32 in/out. d_out: h_tilde | wc | attn (fp32).
#define OUT_WC   524288LL
#define OUT_ATTN 1048576LL
#define C2 2.8853900817779268f   // 2*log2(e)
#define LOG2E 1.4426950408889634f
#define LAS 40                   // proj LDS stride (u16): 32 + 8 pad

// bf16 pool element offsets (in ws at +6MB)
#define P_ENC    0LL
#define P_HID    2097152LL
#define P_WATTN  2621440LL
#define P_WOUTR  3145728LL   // Wout[:,512:] compacted, [n][d] ld 512
#define P_WOUTTL 3407872LL   // Wout[:,:512] transposed, [d][n] ld 512

__device__ inline u16 f2b(float f) {
    return (u16)((__float_as_uint(f) + 0x8000u) >> 16);
}
__device__ inline float b2f(u16 v) { return __uint_as_float(((u32)v) << 16); }
__device__ inline u32 pkcvt(float x, float y) {
    __hip_bfloat162 h = __float22bfloat162_rn(make_float2(x, y));
    return *(u32*)&h;
}
__device__ inline float tanh_fast(float x) {
    return 1.f - 2.f * __builtin_amdgcn_rcpf(__builtin_amdgcn_exp2f(C2 * x) + 1.f);
}

// =============== tobf: bf16 pre-convert + Wout-left transpose ================
// blocks 0..1663: linear convert (enc | hidden | Wattn | WoutR compact)
// blocks 1664..1727: 64x64 LDS-tile transpose of Wout[:, :512] -> WoutTL[d][n]
__global__ __launch_bounds__(256) void tobf(
    const float* __restrict__ enc, const float* __restrict__ hidden,
    const float* __restrict__ Wattn, const float* __restrict__ Wout,
    u16* __restrict__ dst)
{
    const int tid = threadIdx.x;
    if (blockIdx.x < 1664) {
        long long i = ((long long)blockIdx.x * 256 + tid) * 8;
        const float* src;
        if (i < 2097152)      src = enc + i;
        else if (i < 2621440) src = hidden + (i - 2097152);
        else if (i < 3145728) src = Wattn + (i - 2621440);
        else {
            long long j = i - 3145728;                      // WoutR: [n][d] ld512
            src = Wout + ((j >> 9) << 10) + 512 + (j & 511);
        }
        float4 v0 = *(const float4*)src;
        float4 v1 = *(const float4*)(src + 4);
        *(uint4*)(dst + i) = make_uint4(pkcvt(v0.x, v0.y), pkcvt(v0.z, v0.w),
                                        pkcvt(v1.x, v1.y), pkcvt(v1.z, v1.w));
    } else {
        __shared__ u32 lt[64 * 66];
        int tt = blockIdx.x - 1664;
        int n0 = (tt >> 3) * 64, d0 = (tt & 7) * 64;
        int r = tid >> 2, c = (tid & 3) * 16;
        const float* sp = Wout + (long long)(n0 + r) * 1024 + d0 + c;
        #pragma unroll
        for (int q = 0; q < 4; ++q) {
            float4 v = *(const float4*)(sp + q * 4);
            lt[r * 66 + c + q * 4 + 0] = f2b(v.x);
            lt[r * 66 + c + q * 4 + 1] = f2b(v.y);
            lt[r * 66 + c + q * 4 + 2] = f2b(v.z);
            lt[r * 66 + c + q * 4 + 3] = f2b(v.w);
        }
        __syncthreads();
        int dr = tid >> 2, nc = (tid & 3) * 16;
        u32 o[8];
        #pragma unroll
        for (int q = 0; q < 8; ++q) {
            u32 lo = lt[(nc + 2 * q) * 66 + dr];
            u32 hi = lt[(nc + 2 * q + 1) * 66 + dr];
            o[q] = lo | (hi << 16);
        }
        u16* dp = dst + P_WOUTTL + (long long)(d0 + dr) * 512 + n0 + nc;
        *(uint4*)dp       = make_uint4(o[0], o[1], o[2], o[3]);
        *(uint4*)(dp + 8) = make_uint4(o[4], o[5], o[6], o[7]);
    }
}

// =============== proj: ept + hp + hh fused, 768 blocks, 64x64 (R9 revert) ====
// blocks 0..511:   ept[b][k][s] = exp2(C2 * We@enc^T)  (bf16 out)
// blocks 512..639: hp = C2*(hidden@Wh^T + battn)       (f32)
// blocks 640..767: hh = hidden@WoutR^T -> d_out[0..]   (f32, in-place for hout)
__global__ __launch_bounds__(256) void proj(
    const u16* __restrict__ pool, const float* __restrict__ battn,
    float* __restrict__ hp, u16* __restrict__ ept, float* __restrict__ hh)
{
    __shared__ u16 lA[64 * LAS];
    __shared__ u16 lB[64 * LAS];
    const int tid = threadIdx.x;
    const int wvi = tid >> 6, ln = tid & 63;
    const int wm = wvi >> 1, wn = wvi & 1;
    const int l16 = ln & 15, quad = ln >> 4;
    const int blk = blockIdx.x;
    int bx, by, zz = 0, lda, ldb, mode;
    const u16 *A, *B;
    if (blk < 512) {
        mode = 0;
        zz = blk >> 6; by = (blk >> 3) & 7; bx = blk & 7;
        A = pool + P_WATTN + 512; lda = 1024;
        B = pool + P_ENC + (long long)zz * 262144; ldb = 512;
    } else if (blk < 640) {
        mode = 1;
        int i = blk - 512; by = i >> 3; bx = i & 7;
        A = pool + P_HID; lda = 512;
        B = pool + P_WATTN; ldb = 1024;
    } else {
        mode = 2;
        int i = blk - 640; by = i >> 3; bx = i & 7;
        A = pool + P_HID; lda = 512;
        B = pool + P_WOUTR; ldb = 512;
    }
    const int m0 = by * 64, n0 = bx * 64;
    const int srow = tid >> 2, skof = (tid & 3) * 8;
    const u16* Ap = A + (long long)(m0 + srow) * lda + skof;
    const u16* Bp = B + (long long)(n0 + srow) * ldb + skof;

    f32x4 acc00 = {0,0,0,0}, acc01 = {0,0,0,0}, acc10 = {0,0,0,0}, acc11 = {0,0,0,0};

    for (int k0 = 0; k0 < 512; k0 += 32) {
        uint4 av = *(const uint4*)(Ap + k0);
        uint4 bv = *(const uint4*)(Bp + k0);
        __syncthreads();
        *(uint4*)&lA[srow * LAS + skof] = av;
        *(uint4*)&lB[srow * LAS + skof] = bv;
        __syncthreads();
        bf16x8 a0 = *(const bf16x8*)&lA[(wm * 32      + l16) * LAS + quad * 8];
        bf16x8 a1 = *(const bf16x8*)&lA[(wm * 32 + 16 + l16) * LAS + quad * 8];
        bf16x8 b0 = *(const bf16x8*)&lB[(wn * 32      + l16) * LAS + quad * 8];
        bf16x8 b1 = *(const bf16x8*)&lB[(wn * 32 + 16 + l16) * LAS + quad * 8];
        acc00 = __builtin_amdgcn_mfma_f32_16x16x32_bf16(a0, b0, acc00, 0, 0, 0);
        acc01 = __builtin_amdgcn_mfma_f32_16x16x32_bf16(a0, b1, acc01, 0, 0, 0);
        acc10 = __builtin_amdgcn_mfma_f32_16x16x32_bf16(a1, b0, acc10, 0, 0, 0);
        acc11 = __builtin_amdgcn_mfma_f32_16x16x32_bf16(a1, b1, acc11, 0, 0, 0);
    }

    const f32x4* accs[4] = { &acc00, &acc01, &acc10, &acc11 };
    #pragma unroll
    for (int i = 0; i < 2; ++i) {
        #pragma unroll
        for (int j = 0; j < 2; ++j) {
            const f32x4& a = *accs[i * 2 + j];
            #pragma unroll
            for (int r = 0; r < 4; ++r) {
                int m = m0 + wm * 32 + i * 16 + quad * 4 + r;
                int n = n0 + wn * 32 + j * 16 + l16;
                float v = a[r];
                if (mode == 0)
                    ept[(long long)zz * 262144 + (long long)m * 512 + n] =
                        f2b(__builtin_amdgcn_exp2f(C2 * v));
                else if (mode == 1)
                    hp[(long long)m * 512 + n] = C2 * (v + battn[n]);
                else
                    hh[(long long)m * 512 + n] = v;
            }
        }
    }
}

// =============== block reductions (8-wave, 512 threads) ======================
__device__ inline float wred_sum(float v) {
    #pragma unroll
    for (int i = 32; i > 0; i >>= 1) v += __shfl_xor(v, i);
    return v;
}
__device__ inline float bred_sum8(float v, float* red, int tid) {
    v = wred_sum(v);
    __syncthreads();
    if ((tid & 63) == 0) red[tid >> 6] = v;
    __syncthreads();
    float s = 0.f;
    #pragma unroll
    for (int i = 0; i < 8; ++i) s += red[i];
    return s;
}
__device__ inline void bred2_max(float v0, float v1, float* red, int tid,
                                 float* o0, float* o1) {
    #pragma unroll
    for (int i = 32; i > 0; i >>= 1) {
        v0 = fmaxf(v0, __shfl_xor(v0, i));
        v1 = fmaxf(v1, __shfl_xor(v1, i));
    }
    __syncthreads();
    if ((tid & 63) == 0) { red[tid >> 6] = v0; red[8 + (tid >> 6)] = v1; }
    __syncthreads();
    float a0 = red[0], a1 = red[8];
    #pragma unroll
    for (int i = 1; i < 8; ++i) { a0 = fmaxf(a0, red[i]); a1 = fmaxf(a1, red[8 + i]); }
    *o0 = a0; *o1 = a1;
}
__device__ inline void bred2_sum(float v0, float v1, float* red, int tid,
                                 float* o0, float* o1) {
    #pragma unroll
    for (int i = 32; i > 0; i >>= 1) { v0 += __shfl_xor(v0, i); v1 += __shfl_xor(v1, i); }
    __syncthreads();
    if ((tid & 63) == 0) { red[tid >> 6] = v0; red[8 + (tid >> 6)] = v1; }
    __syncthreads();
    float a0 = 0.f, a1 = 0.f;
    #pragma unroll
    for (int i = 0; i < 8; ++i) { a0 += red[i]; a1 += red[8 + i]; }
    *o0 = a0; *o1 = a1;
}

// =============== energies + softmax + wc + h_tilde (fully fused) =============
__device__ inline void proc8(uint4 c, float4 hw, float* a0, float* a1) {
    u32 cc[4] = {c.x, c.y, c.z, c.w};
    #pragma unroll
    for (int i = 0; i < 4; ++i) {
        float xl = __uint_as_float(cc[i] << 16);
        float xh = __uint_as_float(cc[i] & 0xFFFF0000u);
        float rl0 = __builtin_amdgcn_rcpf(fmaf(hw.x, xl, 1.f));
        float rh0 = __builtin_amdgcn_rcpf(fmaf(hw.x, xh, 1.f));
        float rl1 = __builtin_amdgcn_rcpf(fmaf(hw.y, xl, 1.f));
        float rh1 = __builtin_amdgcn_rcpf(fmaf(hw.y, xh, 1.f));
        a0[2*i]   = fmaf(hw.z, rl0, a0[2*i]);
        a0[2*i+1] = fmaf(hw.z, rh0, a0[2*i+1]);
        a1[2*i]   = fmaf(hw.z, rl1, a1[2*i]);
        a1[2*i+1] = fmaf(hw.z, rh1, a1[2*i+1]);
    }
}

__global__ __launch_bounds__(512) void energies(
    const float* __restrict__ maskp, const float* __restrict__ hp,
    const u16* __restrict__ ept, const float* __restrict__ Wv,
    const float* __restrict__ bvp, const u16* __restrict__ pool,
    float* __restrict__ out)
{
    __shared__ __align__(16) float4 hpw[512];   //  8KB
    __shared__ float pa[2][8][512];             // 32KB
    __shared__ __align__(16) float2 aL[512];    //  4KB attn rows
    __shared__ __align__(16) float2 wcL[512];   //  4KB wc rows
    __shared__ float red[16];
    const int tid = threadIdx.x;
    const int b = blockIdx.x >> 6;
    const int t0 = (blockIdx.x & 63) * 2;
    const u16* enc_bf = pool + P_ENC;
    const u16* woutT  = pool + P_WOUTTL;

    float w = Wv[tid];
    float h0 = hp[(long long)(b * 128 + t0) * 512 + tid];
    float h1 = hp[(long long)(b * 128 + t0 + 1) * 512 + tid];
    hpw[tid] = make_float4(__builtin_amdgcn_exp2f(h0), __builtin_amdgcn_exp2f(h1), w, 0.f);
    float sumWv = bred_sum8(w, red, tid);

    const int kg = tid >> 6, sl = tid & 63;
    const int s0 = sl * 8;
    const u16* eb = ept + (long long)b * 262144 + (kg * 64) * 512 + s0;
    const float4* hq = &hpw[kg * 64];

    float a0[8] = {0,0,0,0,0,0,0,0}, a1[8] = {0,0,0,0,0,0,0,0};
    uint4 c0 = *(const uint4*)(eb);
    uint4 c1 = *(const uint4*)(eb + 512);
    uint4 c2 = *(const uint4*)(eb + 1024);
    uint4 c3 = *(const uint4*)(eb + 1536);
    for (int kk = 0; kk < 60; kk += 4) {
        const u16* nb = eb + (kk + 4) * 512;
        uint4 n0 = *(const uint4*)(nb);
        uint4 n1 = *(const uint4*)(nb + 512);
        uint4 n2 = *(const uint4*)(nb + 1024);
        uint4 n3 = *(const uint4*)(nb + 1536);
        proc8(c0, hq[kk],     a0, a1);
        proc8(c1, hq[kk + 1], a0, a1);
        proc8(c2, hq[kk + 2], a0, a1);
        proc8(c3, hq[kk + 3], a0, a1);
        c0 = n0; c1 = n1; c2 = n2; c3 = n3;
    }
    proc8(c0, hq[60], a0, a1);
    proc8(c1, hq[61], a0, a1);
    proc8(c2, hq[62], a0, a1);
    proc8(c3, hq[63], a0, a1);

    *(float4*)&pa[0][kg][s0]     = make_float4(a0[0], a0[1], a0[2], a0[3]);
    *(float4*)&pa[0][kg][s0 + 4] = make_float4(a0[4], a0[5], a0[6], a0[7]);
    *(float4*)&pa[1][kg][s0]     = make_float4(a1[0], a1[1], a1[2], a1[3]);
    *(float4*)&pa[1][kg][s0 + 4] = make_float4(a1[4], a1[5], a1[6], a1[7]);
    __syncthreads();

    const int s = tid;
    float A0 = 0.f, A1 = 0.f;
    #pragma unroll
    for (int g = 0; g < 8; ++g) { A0 += pa[0][g][s]; A1 += pa[1][g][s]; }
    float mv = maskp[(long long)b * 512 + s];
    float bv0 = bvp[0];
    float r0 = (bv0 + sumWv - 2.f * A0) * mv; r0 *= mv;
    float r1 = (bv0 + sumWv - 2.f * A1) * mv; r1 *= mv;

    float mx0, mx1;
    bred2_max(r0, r1, red, tid, &mx0, &mx1);
    float ex0 = __builtin_amdgcn_exp2f((r0 - mx0) * LOG2E) * mv;
    float ex1 = __builtin_amdgcn_exp2f((r1 - mx1) * LOG2E) * mv;
    float sm0, sm1;
    bred2_sum(ex0, ex1, red, tid, &sm0, &sm1);
    float at0 = ex0 * (1.f / (sm0 + 1e-6f));
    float at1 = ex1 * (1.f / (sm1 + 1e-6f));
    out[OUT_ATTN + (long long)(b * 128 + t0) * 512 + s]     = at0;
    out[OUT_ATTN + (long long)(b * 128 + t0 + 1) * 512 + s] = at1;
    aL[s] = make_float2(at0, at1);
    __syncthreads();

    // ---- wc phase: thread owns e = tid ----
    {
        const u16* encb = enc_bf + (long long)b * 262144 + tid;
        const float4* aL4 = (const float4*)aL;
        float acc0 = 0.f, acc1 = 0.f;
        for (int ss = 0; ss < 512; ss += 8) {
            float ev[8];
            #pragma unroll
            for (int i = 0; i < 8; ++i) ev[i] = b2f(encb[(ss + i) * 512]);
            #pragma unroll
            for (int i = 0; i < 4; ++i) {
                float4 ap = aL4[(ss >> 1) + i];
                acc0 = fmaf(ap.x, ev[2*i],   acc0);
                acc1 = fmaf(ap.y, ev[2*i],   acc1);
                acc0 = fmaf(ap.z, ev[2*i+1], acc0);
                acc1 = fmaf(ap.w, ev[2*i+1], acc1);
            }
        }
        out[OUT_WC + (long long)(b * 128 + t0) * 512 + tid]     = acc0;
        out[OUT_WC + (long long)(b * 128 + t0 + 1) * 512 + tid] = acc1;
        wcL[tid] = make_float2(acc0, acc1);
    }
    __syncthreads();

    // ---- h_tilde phase: thread owns n = tid ----
    {
        const u16* wt = woutT + tid;           // WoutT[d][n], coalesced over n
        const float4* wL4 = (const float4*)wcL;
        float acc0 = 0.f, acc1 = 0.f;
        for (int dd = 0; dd < 512; dd += 8) {
            float wv[8];
            #pragma unroll
            for (int i = 0; i < 8; ++i) wv[i] = b2f(wt[(dd + i) * 512]);
            #pragma unroll
            for (int i = 0; i < 4; ++i) {
                float4 cp = wL4[(dd >> 1) + i];
                acc0 = fmaf(cp.x, wv[2*i],   acc0);
                acc1 = fmaf(cp.y, wv[2*i],   acc1);
                acc0 = fmaf(cp.z, wv[2*i+1], acc0);
                acc1 = fmaf(cp.w, wv[2*i+1], acc1);
            }
        }
        long long o0 = (long long)(b * 128 + t0) * 512 + tid;
        long long o1 = (long long)(b * 128 + t0 + 1) * 512 + tid;
        out[o0] = tanh_fast(acc0 + out[o0]);   // out holds hh from proj
        out[o1] = tanh_fast(acc1 + out[o1]);
    }
}

extern "C" void kernel_launch(void* const* d_in, const int* in_sizes, int n_in,
                              void* d_out, int out_size, void* d_ws, size_t ws_size,
                              hipStream_t stream)
{
    const float* hidden = (const float*)d_in[0];
    const float* enc    = (const float*)d_in[1];
    const float* mask   = (const float*)d_in[2];
    const float* Wattn  = (const float*)d_in[3];
    const float* battn  = (const float*)d_in[4];
    const float* Wv     = (const float*)d_in[5];
    const float* bvp    = (const float*)d_in[6];
    const float* Wout   = (const float*)d_in[7];
    float* out = (float*)d_out;

    float* hp  = (float*)d_ws;                      // @0   2MB fp32
    u16*   ept = (u16*)((char*)d_ws + (2 << 20));   // @2M  4MB bf16 (exp2 domain)
    u16*   pool = (u16*)((char*)d_ws + (6 << 20));  // @6M  ~7.3MB bf16 pool

    tobf<<<1728, 256, 0, stream>>>(enc, hidden, Wattn, Wout, pool);
    proj<<<768, 256, 0, stream>>>(pool, battn, hp, ept, out /* hh in-place */);
    energies<<<512, 512, 0, stream>>>(mask, hp, ept, Wv, bvp, pool, out);
}